// Round 9
// baseline (223.612 us; speedup 1.0000x reference)
//
#include <hip/hip_runtime.h>
#include <math.h>

typedef unsigned short u16;
typedef __attribute__((ext_vector_type(8))) short bf16x8;
typedef __attribute__((ext_vector_type(4))) float f32x4;

#define MFMA16(a, b, c) __builtin_amdgcn_mfma_f32_16x16x32_bf16((a), (b), (c), 0, 0, 0)

#define B_ 2
#define S_ 2048
#define HID_ 2048
#define NH_ 16
#define NKV_ 4
#define HD_ 128
#define SCALE_ 0.08838834764831845f

static __device__ __forceinline__ u16 f2bf(float f) {
  unsigned u = __float_as_uint(f);
  u = (u + 0x7FFFu + ((u >> 16) & 1u)) >> 16;
  return (u16)u;
}

#define GLDS(src, dst)                                                        \
  __builtin_amdgcn_global_load_lds(                                           \
      (const __attribute__((address_space(1))) void*)(src),                   \
      (__attribute__((address_space(3))) void*)(dst), 16, 0, 0)

#define BAR __builtin_amdgcn_s_barrier()
// rule #18: lgkmcnt(0) asm must be followed by sched_barrier(0)
#define LGKM0                                                                 \
  do {                                                                        \
    asm volatile("s_waitcnt lgkmcnt(0)" ::: "memory");                        \
    __builtin_amdgcn_sched_barrier(0);                                        \
  } while (0)

template <int N>
static __device__ __forceinline__ void waitv() {
  if constexpr (N == 0) asm volatile("s_waitcnt vmcnt(0)" ::: "memory");
  else if constexpr (N == 4) asm volatile("s_waitcnt vmcnt(4)" ::: "memory");
  else if constexpr (N == 6) asm volatile("s_waitcnt vmcnt(6)" ::: "memory");
}

// Stage a tile (rows x (1<<CPRL) 16B-chunks per row) from global into LDS.
// 256-thread version (attn). LDS[r][bir] holds global[r][bir ^ ((r&7)<<4)].
template <int CPRL>
static __device__ __forceinline__ void stage_tile(const char* g0, long gstride,
                                                  char* lds) {
  int tid = threadIdx.x;
  int lane = tid & 63, wv = tid >> 6;
#pragma unroll
  for (int it = 0; it < 4; ++it) {
    int cb = wv * 256 + it * 64;  // wave-uniform chunk base
    int c = cb + lane;
    int r = c >> CPRL;
    int bir = (c & ((1 << CPRL) - 1)) << 4;
    int sbir = bir ^ ((r & 7) << 4);
    GLDS(g0 + (long)r * gstride + sbir, lds + cb * 16);
  }
}

// ---------------- prep kernels ----------------

__global__ __launch_bounds__(256) void conv_x(const float* __restrict__ x,
                                              u16* __restrict__ y) {
  size_t i = ((size_t)blockIdx.x * 256 + threadIdx.x) * 4;
  float4 v = *(const float4*)(x + i);
  ushort4 o = make_ushort4(f2bf(v.x), f2bf(v.y), f2bf(v.z), f2bf(v.w));
  *(ushort4*)(y + i) = o;
}

// dst[n*K + k] = bf16(src[k*N + n]);  grid: (N/32, K/32), block (32,8)
__global__ __launch_bounds__(256) void transpose_bf16(
    const float* __restrict__ src, u16* __restrict__ dst, int K, int N) {
  __shared__ float t[32][33];
  int n0 = blockIdx.x * 32, k0 = blockIdx.y * 32;
  int tx = threadIdx.x, ty = threadIdx.y;
#pragma unroll
  for (int i = 0; i < 4; ++i)
    t[ty + 8 * i][tx] = src[(size_t)(k0 + ty + 8 * i) * N + n0 + tx];
  __syncthreads();
#pragma unroll
  for (int i = 0; i < 4; ++i)
    dst[(size_t)(n0 + ty + 8 * i) * K + k0 + tx] = f2bf(t[tx][ty + 8 * i]);
}

__global__ __launch_bounds__(256) void prep_cstab(const int* __restrict__ pos,
                                                  float2* __restrict__ cs) {
  int i = blockIdx.x * 256 + threadIdx.x;  // [B*S * 64)
  int row = i >> 6, d = i & 63;
  float p = (float)pos[row];
  float inv = expf(-((float)(2 * d) * (1.0f / 128.0f)) * 13.815510557964274f);
  float a = p * inv;
  float s, c;
  sincosf(a, &s, &c);
  cs[i] = make_float2(c, s);
}

// ------- register-persist pipelined GEMM core (512 threads, 8 waves) -------
// Key fix vs R6-R8 (all ~24% MfmaUtil): those re-read A/B frags per phase
// (48 b128/wave/K-tile) -> LDS-read-BW-bound. Here each frag is read ONCE:
// all A-frags persist in registers across the K-tile (fa[2][MA], 32 VGPR),
// phases iterate B-groups of 2 frags -> 8+16 = 24 b128/wave/K-tile.
// Phases/K-tile = NG = (BN/WN)/32 (4 for 256-wide waves, 2 for 64).
// B halves interleaved on col bit5 so group order {0,1},{4,5} (h0) then
// {2,3},{6,7} (h1) lets h1 arrive one phase later. Counted vmcnt (never 0
// except last tile): derivation in-line; stage-issue >=4 barriers after the
// target region's last reader (race-free). Swizzle: 16B chunk j ^ (g&7)
// within each 128B row -> ~2-way bank aliasing on stage and b128 reads.
template <int BM, int BN, int WM, int WN>
static __device__ __forceinline__ void gemm_rp(
    const u16* __restrict__ A, const u16* __restrict__ Bt, int K, int bm,
    int bn, char* __restrict__ Abuf, char* __restrict__ Bbuf,
    f32x4 (&acc)[(BM / WM) / 16][(BN / WN) / 16]) {
  constexpr int PWM = BM / WM, PWN = BN / WN;
  constexpr int MA = PWM / 16;   // A frags per wave (persist)
  constexpr int NG = (PWN / 16) / 2;  // B groups = phases per K-tile
  constexpr int AU = BM / 128;   // A stage units (2 GLDS/thread each)
  constexpr int ABYTES = BM * 128;
  constexpr int HB = BN / 2;     // rows per B half

  int tid = threadIdx.x, lane = tid & 63, wid = tid >> 6;
  int l16 = lane & 15, ln4 = lane >> 4;
  int wr = wid / WN, wc = wid % WN;

  const char* ga = (const char*)(A + (size_t)bm * BM * K);
  const char* gb = (const char*)(Bt + (size_t)bn * BN * K);
  long gs = (long)K * 2;
  int nkt = K / 64;

  auto stA = [&](int t, int u, int p) {  // rows u*128 .. u*128+127
    if (t >= nkt) return;
#pragma unroll
    for (int it = 0; it < 2; ++it) {
      int c = it * 512 + tid;
      int g = c >> 3, j = c & 7;
      int R = u * 128 + g;
      GLDS(ga + (long)R * gs + t * 128 + ((j ^ (g & 7)) << 4),
           Abuf + p * ABYTES + u * 16384 + c * 16);
    }
  };
  auto stB = [&](int t, int h, int p) {  // rows with bit5 == h
    if (t >= nkt) return;
#pragma unroll
    for (int it = 0; it < HB / 64; ++it) {
      int c = it * 512 + tid;
      int g = c >> 3, j = c & 7;
      int R = (g & 31) | (h << 5) | ((g >> 5) << 6);
      GLDS(gb + (long)R * gs + t * 128 + ((j ^ (g & 7)) << 4),
           Bbuf + p * (BN * 128) + h * (HB * 128) + c * 16);
    }
  };

  bf16x8 fa[2][MA], fb[2][2];
  auto LDA = [&](int p) {
#pragma unroll
    for (int kk = 0; kk < 2; ++kk)
#pragma unroll
      for (int m = 0; m < MA; ++m) {
        int r = wr * PWM + m * 16 + l16;
        fa[kk][m] = *(const bf16x8*)(Abuf + p * ABYTES + r * 128 +
                                     (((kk * 4 + ln4) ^ (r & 7)) << 4));
      }
  };
  auto LDB1 = [&](int p, int j, int n) {
#pragma unroll
    for (int kk = 0; kk < 2; ++kk) {
      int r = wc * PWN + n * 16 + l16;
      int h = (r >> 5) & 1;
      int g = (r & 31) | ((r >> 6) << 5);
      fb[kk][j] = *(const bf16x8*)(Bbuf + p * (BN * 128) + h * (HB * 128) +
                                   g * 128 + (((kk * 4 + ln4) ^ (g & 7)) << 4));
    }
  };
  auto MM = [&](int n0, int n1) {
    __builtin_amdgcn_s_setprio(1);
#pragma unroll
    for (int kk = 0; kk < 2; ++kk)
#pragma unroll
      for (int m = 0; m < MA; ++m) {
        acc[m][n0] = MFMA16(fa[kk][m], fb[kk][0], acc[m][n0]);
        acc[m][n1] = MFMA16(fa[kk][m], fb[kk][1], acc[m][n1]);
      }
    __builtin_amdgcn_s_setprio(0);
  };

  // prologue: tile 0 fully into buf 0, stream order A-units, Bh0, Bh1
#pragma unroll
  for (int u = 0; u < AU; ++u) stA(0, u, 0);
  stB(0, 0, 0);
  stB(0, 1, 0);

  if constexpr (NG == 4) {
    // per-tile stage stream: ph0:A1' ph1:A2' ph2:Bh0' ph3:Bh1' (2 instr each)
    // entering ph0 (steady): outstanding 8 (t's units) +2 new -> vmcnt(4)
    //   drains t's A1,A2,Bh0 (Bh1 + A1' in flight)
    // entering ph2: outstanding Bh1(2)+A1'A2'Bh0'(6) -> vmcnt(6) drains Bh1
#pragma unroll 1
    for (int t = 0; t < nkt; ++t) {
      int p = t & 1, q = p ^ 1;
      bool nl = (t + 1 < nkt);
      // ph0: needs A(all)+Bh0; groups {0,1}
      stA(t + 1, 0, q);
      if (nl) waitv<4>(); else waitv<0>();
      BAR;
      LDA(p); LDB1(p, 0, 0); LDB1(p, 1, 1);
      LGKM0; MM(0, 1);
      BAR;
      // ph1: {4,5} in h0 (ready since ph0)
      LDB1(p, 0, 4); LDB1(p, 1, 5);
      stA(t + 1, 1, q);
      BAR; LGKM0; MM(4, 5); BAR;
      // ph2: {2,3} in h1 (needs t's Bh1)
      stB(t + 1, 0, q);
      if (nl) waitv<6>(); else waitv<0>();
      BAR;
      LDB1(p, 0, 2); LDB1(p, 1, 3);
      LGKM0; MM(2, 3);
      BAR;
      // ph3: {6,7} in h1 (ready)
      LDB1(p, 0, 6); LDB1(p, 1, 7);
      stB(t + 1, 1, q);
      BAR; LGKM0; MM(6, 7); BAR;
    }
  } else {
    // NG == 2. stage stream: ph0: A'+Bh0' (4), ph1: Bh1' (2)
    // entering ph0 (steady): outstanding 6 (t's) +4 new -> vmcnt(6) drains
    //   t's A,Bh0. entering ph1: Bh1(2)+A'Bh0'(4)+Bh1'(2) -> vmcnt(6).
#pragma unroll 1
    for (int t = 0; t < nkt; ++t) {
      int p = t & 1, q = p ^ 1;
      bool nl = (t + 1 < nkt);
      // ph0: groups {0,1} (h0)
      stA(t + 1, 0, q);
      stB(t + 1, 0, q);
      if (nl) waitv<6>(); else waitv<0>();
      BAR;
      LDA(p); LDB1(p, 0, 0); LDB1(p, 1, 1);
      LGKM0; MM(0, 1);
      BAR;
      // ph1: {2,3} (h1, needs t's Bh1)
      stB(t + 1, 1, q);
      if (nl) waitv<6>(); else waitv<0>();
      BAR;
      LDB1(p, 0, 2); LDB1(p, 1, 3);
      LGKM0; MM(2, 3);
      BAR;
    }
  }
}

// ---------------- GEMM1: QKV projection + bias + RoPE ----------------
// C[4096,3072] = Xb @ Wqkv_t^T. BM=BN=256, waves 4(M)x2(N): per-wave 64 rows
// x 128 cols (one head-block) -> RoPE pairs (d,d+64) = acc frags (bi,bi+4)
// lane-local. Q pre-scaled by SCALE_.
__global__ __launch_bounds__(512, 2) void gemm_qkv(
    const u16* __restrict__ Xb, const u16* __restrict__ Wt,
    const float* __restrict__ bq, const float* __restrict__ bk,
    const float* __restrict__ bv, const float2* __restrict__ cstab,
    u16* __restrict__ Qh, u16* __restrict__ Kh, u16* __restrict__ Vt) {
  __shared__ __align__(16) char Abuf[2 * 256 * 128];  // 64 KB
  __shared__ __align__(16) char Bbuf[2 * 256 * 128];  // 64 KB
  int bid = blockIdx.x;
  int swz = (bid & 7) * 24 + (bid >> 3);  // XCD-contiguous chunks (192=8*24)
  int bm = swz / 12, bn = swz % 12;

  f32x4 acc[4][8] = {};
  gemm_rp<256, 256, 4, 2>(Xb, Wt, 2048, bm, bn, Abuf, Bbuf, acc);

  int tid = threadIdx.x, lane = tid & 63, wid = tid >> 6;
  int l16 = lane & 15, ln4 = lane >> 4;
  int wr = wid >> 1, wc = wid & 1;

  int cb = bn * 2 + wc;  // global 128-col head-block
  int region, hh;
  const float* bias;
  if (cb < 16) {
    region = 0; hh = cb; bias = bq;
  } else if (cb < 20) {
    region = 1; hh = cb - 16; bias = bk;
  } else {
    region = 2; hh = cb - 20; bias = bv;
  }
  float postscale = (region == 0) ? SCALE_ : 1.0f;

#pragma unroll
  for (int bi = 0; bi < 4; ++bi) {
    int dlo = bi * 16 + l16;  // 0..63
    float blo = bias[hh * 128 + dlo];
    float bhi = bias[hh * 128 + dlo + 64];
#pragma unroll
    for (int m = 0; m < 4; ++m) {
      int rbase = bm * 256 + wr * 64 + m * 16 + ln4 * 4;
      int bb = rbase >> 11;   // batch
      int s0 = rbase & 2047;  // seq
      if (region == 2) {
        // V: no rope; transposed store Vt[b][kvh][d][s], 4 consecutive s
        u16 pl[4], ph[4];
#pragma unroll
        for (int reg = 0; reg < 4; ++reg) {
          pl[reg] = f2bf(acc[m][bi][reg] + blo);
          ph[reg] = f2bf(acc[m][bi + 4][reg] + bhi);
        }
        size_t base = ((size_t)(bb * NKV_ + hh) * 128 + dlo) * 2048 + s0;
        *(ushort4*)(Vt + base) = make_ushort4(pl[0], pl[1], pl[2], pl[3]);
        *(ushort4*)(Vt + base + (size_t)64 * 2048) =
            make_ushort4(ph[0], ph[1], ph[2], ph[3]);
      } else {
#pragma unroll
        for (int reg = 0; reg < 4; ++reg) {
          int rg = rbase + reg;
          int s = rg & 2047;
          float vlo = acc[m][bi][reg] + blo;
          float vhi = acc[m][bi + 4][reg] + bhi;
          float2 cs = cstab[(size_t)rg * 64 + dlo];
          float nl = (vlo * cs.x - vhi * cs.y) * postscale;
          float nh = (vhi * cs.x + vlo * cs.y) * postscale;
          u16* dst = (region == 0)
                         ? Qh + ((size_t)(bb * NH_ + hh) * 2048 + s) * 128
                         : Kh + ((size_t)(bb * NKV_ + hh) * 2048 + s) * 128;
          dst[dlo] = f2bf(nl);
          dst[dlo + 64] = f2bf(nh);
        }
      }
    }
  }
}

// ---------------- attention: causal GQA flash ----------------
// R6 version (best measured: 78.8us). 4 waves, single-buffered 40KB LDS
// (4 blocks/CU), XCD pinning (bid&7 -> (b,kvh)), defer-max softmax.
__global__ __launch_bounds__(256) void attn(const u16* __restrict__ Qh,
                                            const u16* __restrict__ Kh,
                                            const u16* __restrict__ Vt,
                                            u16* __restrict__ ctx) {
  __shared__ __align__(16) char Ks[16384];   // [64 kv][128 d] swizzled
  __shared__ __align__(16) char Vs[16384];   // [128 d][64 kv] swizzled
  __shared__ __align__(16) char Ps[4][2048]; // per-wave [16 q][64 kv]
  int bid = blockIdx.x;
  int x = bid & 7;           // XCD group = (b, kvh)
  int b = x >> 2, kvh = x & 3;
  int i = bid >> 3;          // 0..127 within XCD group
  int hl = i & 3;            // head within kv group
  int qt = 31 - (i >> 2);    // heavy q-tiles first
  int h = kvh * 4 + hl;
  int q0 = qt * 64;
  int nt = qt + 1;

  int tid = threadIdx.x, lane = tid & 63, w = tid >> 6;
  int l16 = lane & 15, ln4 = lane >> 4;

  bf16x8 qf[4];
  const u16* qrow = Qh + ((size_t)(b * NH_ + h) * 2048 + q0 + w * 16 + l16) * 128;
#pragma unroll
  for (int kk = 0; kk < 4; ++kk)
    qf[kk] = *(const bf16x8*)(qrow + kk * 32 + ln4 * 8);

  f32x4 oacc[8] = {};
  float mrow[4], lsum[4];
#pragma unroll
  for (int r = 0; r < 4; ++r) {
    mrow[r] = -1e30f;
    lsum[r] = 0.0f;
  }

  const char* kbase = (const char*)(Kh + (size_t)(b * NKV_ + kvh) * 2048 * 128);
  const char* vbase = (const char*)(Vt + (size_t)(b * NKV_ + kvh) * 128 * 2048);

#pragma unroll 1
  for (int t = 0; t < nt; ++t) {
    __syncthreads();
    stage_tile<4>(kbase + (size_t)t * 64 * 256, 256, Ks);
    stage_tile<3>(vbase + (size_t)t * 128, 4096, Vs);
    __syncthreads();

    // S = Q K^T
    f32x4 sa[4] = {};
    __builtin_amdgcn_s_setprio(1);
#pragma unroll
    for (int kk = 0; kk < 4; ++kk) {
      bf16x8 kf[4];
#pragma unroll
      for (int n = 0; n < 4; ++n) {
        int r = n * 16 + l16;
        int off = r * 256 + ((kk * 64 + ln4 * 16) ^ ((r & 7) << 4));
        kf[n] = *(const bf16x8*)(Ks + off);
      }
#pragma unroll
      for (int n = 0; n < 4; ++n) sa[n] = MFMA16(qf[kk], kf[n], sa[n]);
    }
    __builtin_amdgcn_s_setprio(0);

    if (t == nt - 1) {
#pragma unroll
      for (int n = 0; n < 4; ++n)
#pragma unroll
        for (int reg = 0; reg < 4; ++reg)
          if (t * 64 + n * 16 + l16 > q0 + w * 16 + ln4 * 4 + reg)
            sa[n][reg] = -1e30f;
    }

    // shuffle-free defer-max test
    float tloc[4];
    int ok = 1;
#pragma unroll
    for (int reg = 0; reg < 4; ++reg) {
      tloc[reg] = fmaxf(fmaxf(sa[0][reg], sa[1][reg]),
                        fmaxf(sa[2][reg], sa[3][reg]));
      ok &= (tloc[reg] <= mrow[reg] + 8.0f);
    }
    if (!__all(ok)) {
#pragma unroll
      for (int reg = 0; reg < 4; ++reg) {
        float tm = tloc[reg];
#pragma unroll
        for (int mk = 1; mk < 16; mk <<= 1) tm = fmaxf(tm, __shfl_xor(tm, mk));
        float mnew = fmaxf(mrow[reg], tm);
        float scl = __expf(mrow[reg] - mnew);
        mrow[reg] = mnew;
        lsum[reg] *= scl;
#pragma unroll
        for (int nf = 0; nf < 8; ++nf) oacc[nf][reg] *= scl;
      }
    }

    // P = exp(S - m) -> wave-private LDS; per-lane lsum partials
#pragma unroll
    for (int reg = 0; reg < 4; ++reg) {
      int prow = ln4 * 4 + reg;
      float rs = 0.0f;
#pragma unroll
      for (int n = 0; n < 4; ++n) {
        float p = __expf(sa[n][reg] - mrow[reg]);
        rs += p;
        int off = prow * 128 + ((2 * (n * 16 + l16)) ^ ((prow & 7) << 4));
        *(u16*)(Ps[w] + off) = f2bf(p);
      }
      lsum[reg] += rs;
    }

    // O += P V
    __builtin_amdgcn_s_setprio(1);
#pragma unroll
    for (int kc = 0; kc < 2; ++kc) {
      int offa = l16 * 128 + ((kc * 64 + ln4 * 16) ^ ((l16 & 7) << 4));
      bf16x8 pa = *(const bf16x8*)(Ps[w] + offa);
#pragma unroll
      for (int nf = 0; nf < 8; ++nf) {
        int r = nf * 16 + l16;
        int off = r * 128 + ((kc * 64 + ln4 * 16) ^ ((r & 7) << 4));
        bf16x8 vf = *(const bf16x8*)(Vs + off);
        oacc[nf] = MFMA16(pa, vf, oacc[nf]);
      }
    }
    __builtin_amdgcn_s_setprio(0);
  }

  // epilogue
#pragma unroll
  for (int reg = 0; reg < 4; ++reg) {
#pragma unroll
    for (int mk = 1; mk < 16; mk <<= 1)
      lsum[reg] += __shfl_xor(lsum[reg], mk);
  }
#pragma unroll
  for (int reg = 0; reg < 4; ++reg) {
    float inv = 1.0f / lsum[reg];
    int s = q0 + w * 16 + ln4 * 4 + reg;
#pragma unroll
    for (int nf = 0; nf < 8; ++nf) {
      ctx[((size_t)(b * 2048 + s)) * 2048 + h * 128 + nf * 16 + l16] =
          f2bf(oacc[nf][reg] * inv);
    }
  }
}

// ---------------- GEMM2: out = ctx @ Wo (fp32 out) ----------------
// BM=128, BN=256, waves 2(M)x4(N): per-wave 64x64. Grid = 256 blocks.
__global__ __launch_bounds__(512, 2) void gemm_out(const u16* __restrict__ Ab,
                                                   const u16* __restrict__ Wt,
                                                   float* __restrict__ out) {
  __shared__ __align__(16) char Abuf[2 * 128 * 128];  // 32 KB
  __shared__ __align__(16) char Bbuf[2 * 256 * 128];  // 64 KB
  int bid = blockIdx.x;
  int swz = (bid & 7) * 32 + (bid >> 3);  // XCD chunks (256=8*32)
  int bm = swz >> 3, bn = swz & 7;

  f32x4 acc[4][4] = {};
  gemm_rp<128, 256, 2, 4>(Ab, Wt, 2048, bm, bn, Abuf, Bbuf, acc);

  int tid = threadIdx.x, lane = tid & 63, wid = tid >> 6;
  int l16 = lane & 15, ln4 = lane >> 4;
  int wr = wid >> 2, wc = wid & 3;

#pragma unroll
  for (int m = 0; m < 4; ++m)
#pragma unroll
    for (int n = 0; n < 4; ++n)
#pragma unroll
      for (int reg = 0; reg < 4; ++reg) {
        int row = bm * 128 + wr * 64 + m * 16 + ln4 * 4 + reg;
        int col = bn * 256 + wc * 64 + n * 16 + l16;
        out[(size_t)row * 2048 + col] = acc[m][n][reg];
      }
}

// ---------------- launch ----------------

extern "C" void kernel_launch(void* const* d_in, const int* in_sizes, int n_in,
                              void* d_out, int out_size, void* d_ws,
                              size_t ws_size, hipStream_t stream) {
  const float* hid = (const float*)d_in[0];
  const int* pos = (const int*)d_in[1];
  const float* Wq = (const float*)d_in[2];
  const float* bq = (const float*)d_in[3];
  const float* Wk = (const float*)d_in[4];
  const float* bk = (const float*)d_in[5];
  const float* Wv = (const float*)d_in[6];
  const float* bv = (const float*)d_in[7];
  const float* Wo = (const float*)d_in[8];
  float* out = (float*)d_out;

  char* ws = (char*)d_ws;
  u16* Xb = (u16*)(ws + 0);                    // 16.78 MB  [4096][2048] bf16
  u16* Wqkvt = (u16*)(ws + 16777216UL);        // 12.58 MB  [3072][2048] bf16
  u16* Wot = (u16*)(ws + 29360128UL);          //  8.39 MB  [2048][2048] bf16
  u16* Qh = (u16*)(ws + 37748736UL);           // 16.78 MB  [B][NH][S][D]
  u16* Kh = (u16*)(ws + 54525952UL);           //  4.19 MB  [B][NKV][S][D]
  u16* Vt = (u16*)(ws + 58720256UL);           //  4.19 MB  [B][NKV][D][S]
  float2* cstab = (float2*)(ws + 62914560UL);  //  2.10 MB  [B*S][64]
  u16* ctx = Xb;  // alias: Xb dead after gemm_qkv

  conv_x<<<8192, 256, 0, stream>>>(hid, Xb);
  transpose_bf16<<<dim3(64, 64), dim3(32, 8), 0, stream>>>(Wq, Wqkvt, 2048,
                                                           2048);
  transpose_bf16<<<dim3(16, 64), dim3(32, 8), 0, stream>>>(
      Wk, Wqkvt + (size_t)2048 * 2048, 2048, 512);
  transpose_bf16<<<dim3(16, 64), dim3(32, 8), 0, stream>>>(
      Wv, Wqkvt + (size_t)2560 * 2048, 2048, 512);
  transpose_bf16<<<dim3(64, 64), dim3(32, 8), 0, stream>>>(Wo, Wot, 2048, 2048);
  prep_cstab<<<1024, 256, 0, stream>>>(pos, cstab);

  gemm_qkv<<<192, 512, 0, stream>>>(Xb, Wqkvt, bq, bk, bv, cstab, Qh, Kh, Vt);
  attn<<<1024, 256, 0, stream>>>(Qh, Kh, Vt, ctx);
  gemm_out<<<256, 512, 0, stream>>>(ctx, Wot, out);
}

// Round 10
// 222.106 us; speedup vs baseline: 1.0068x; 1.0068x over previous
//
#include <hip/hip_runtime.h>
#include <math.h>

typedef unsigned short u16;
typedef __attribute__((ext_vector_type(8))) short bf16x8;
typedef __attribute__((ext_vector_type(4))) float f32x4;

#define MFMA16(a, b, c) __builtin_amdgcn_mfma_f32_16x16x32_bf16((a), (b), (c), 0, 0, 0)

#define B_ 2
#define S_ 2048
#define HID_ 2048
#define NH_ 16
#define NKV_ 4
#define HD_ 128
#define SCALE_ 0.08838834764831845f

static __device__ __forceinline__ u16 f2bf(float f) {
  unsigned u = __float_as_uint(f);
  u = (u + 0x7FFFu + ((u >> 16) & 1u)) >> 16;
  return (u16)u;
}

#define GLDS(src, dst)                                                        \
  __builtin_amdgcn_global_load_lds(                                           \
      (const __attribute__((address_space(1))) void*)(src),                   \
      (__attribute__((address_space(3))) void*)(dst), 16, 0, 0)

#define BAR __builtin_amdgcn_s_barrier()
// rule #18: lgkmcnt(0) asm must be followed by sched_barrier(0)
#define LGKM0                                                                 \
  do {                                                                        \
    asm volatile("s_waitcnt lgkmcnt(0)" ::: "memory");                        \
    __builtin_amdgcn_sched_barrier(0);                                        \
  } while (0)

template <int N>
static __device__ __forceinline__ void waitv() {
  if constexpr (N == 0) asm volatile("s_waitcnt vmcnt(0)" ::: "memory");
  else if constexpr (N == 2) asm volatile("s_waitcnt vmcnt(2)" ::: "memory");
  else if constexpr (N == 4) asm volatile("s_waitcnt vmcnt(4)" ::: "memory");
  else if constexpr (N == 6) asm volatile("s_waitcnt vmcnt(6)" ::: "memory");
}

// Stage a tile (rows x (1<<CPRL) 16B-chunks per row) from global into LDS.
// 256-thread version (attn). LDS[r][bir] holds global[r][bir ^ ((r&7)<<4)].
template <int CPRL>
static __device__ __forceinline__ void stage_tile(const char* g0, long gstride,
                                                  char* lds) {
  int tid = threadIdx.x;
  int lane = tid & 63, wv = tid >> 6;
#pragma unroll
  for (int it = 0; it < 4; ++it) {
    int cb = wv * 256 + it * 64;  // wave-uniform chunk base
    int c = cb + lane;
    int r = c >> CPRL;
    int bir = (c & ((1 << CPRL) - 1)) << 4;
    int sbir = bir ^ ((r & 7) << 4);
    GLDS(g0 + (long)r * gstride + sbir, lds + cb * 16);
  }
}

// ---------------- prep kernels ----------------

__global__ __launch_bounds__(256) void conv_x(const float* __restrict__ x,
                                              u16* __restrict__ y) {
  size_t i = ((size_t)blockIdx.x * 256 + threadIdx.x) * 4;
  float4 v = *(const float4*)(x + i);
  ushort4 o = make_ushort4(f2bf(v.x), f2bf(v.y), f2bf(v.z), f2bf(v.w));
  *(ushort4*)(y + i) = o;
}

// dst[n*K + k] = bf16(src[k*N + n]);  grid: (N/32, K/32), block (32,8)
__global__ __launch_bounds__(256) void transpose_bf16(
    const float* __restrict__ src, u16* __restrict__ dst, int K, int N) {
  __shared__ float t[32][33];
  int n0 = blockIdx.x * 32, k0 = blockIdx.y * 32;
  int tx = threadIdx.x, ty = threadIdx.y;
#pragma unroll
  for (int i = 0; i < 4; ++i)
    t[ty + 8 * i][tx] = src[(size_t)(k0 + ty + 8 * i) * N + n0 + tx];
  __syncthreads();
#pragma unroll
  for (int i = 0; i < 4; ++i)
    dst[(size_t)(n0 + ty + 8 * i) * K + k0 + tx] = f2bf(t[tx][ty + 8 * i]);
}

__global__ __launch_bounds__(256) void prep_cstab(const int* __restrict__ pos,
                                                  float2* __restrict__ cs) {
  int i = blockIdx.x * 256 + threadIdx.x;  // [B*S * 64)
  int row = i >> 6, d = i & 63;
  float p = (float)pos[row];
  float inv = expf(-((float)(2 * d) * (1.0f / 128.0f)) * 13.815510557964274f);
  float a = p * inv;
  float s, c;
  sincosf(a, &s, &c);
  cs[i] = make_float2(c, s);
}

// ------- register-persist pipelined GEMM core (512 threads, 8 waves) -------
// Used by gemm_out. Phases iterate B-groups; A persists in regs per K-tile.
template <int BM, int BN, int WM, int WN>
static __device__ __forceinline__ void gemm_rp(
    const u16* __restrict__ A, const u16* __restrict__ Bt, int K, int bm,
    int bn, char* __restrict__ Abuf, char* __restrict__ Bbuf,
    f32x4 (&acc)[(BM / WM) / 16][(BN / WN) / 16]) {
  constexpr int PWM = BM / WM, PWN = BN / WN;
  constexpr int MA = PWM / 16;
  constexpr int AU = BM / 128;
  constexpr int ABYTES = BM * 128;
  constexpr int HB = BN / 2;

  int tid = threadIdx.x, lane = tid & 63, wid = tid >> 6;
  int l16 = lane & 15, ln4 = lane >> 4;
  int wr = wid / WN, wc = wid % WN;

  const char* ga = (const char*)(A + (size_t)bm * BM * K);
  const char* gb = (const char*)(Bt + (size_t)bn * BN * K);
  long gs = (long)K * 2;
  int nkt = K / 64;

  auto stA = [&](int t, int u, int p) {
    if (t >= nkt) return;
#pragma unroll
    for (int it = 0; it < 2; ++it) {
      int c = it * 512 + tid;
      int g = c >> 3, j = c & 7;
      int R = u * 128 + g;
      GLDS(ga + (long)R * gs + t * 128 + ((j ^ (g & 7)) << 4),
           Abuf + p * ABYTES + u * 16384 + c * 16);
    }
  };
  auto stB = [&](int t, int h, int p) {
    if (t >= nkt) return;
#pragma unroll
    for (int it = 0; it < HB / 64; ++it) {
      int c = it * 512 + tid;
      int g = c >> 3, j = c & 7;
      int R = (g & 31) | (h << 5) | ((g >> 5) << 6);
      GLDS(gb + (long)R * gs + t * 128 + ((j ^ (g & 7)) << 4),
           Bbuf + p * (BN * 128) + h * (HB * 128) + c * 16);
    }
  };

  bf16x8 fa[2][MA], fb[2][2];
  auto LDA = [&](int p) {
#pragma unroll
    for (int kk = 0; kk < 2; ++kk)
#pragma unroll
      for (int m = 0; m < MA; ++m) {
        int r = wr * PWM + m * 16 + l16;
        fa[kk][m] = *(const bf16x8*)(Abuf + p * ABYTES + r * 128 +
                                     (((kk * 4 + ln4) ^ (r & 7)) << 4));
      }
  };
  auto LDB1 = [&](int p, int j, int n) {
#pragma unroll
    for (int kk = 0; kk < 2; ++kk) {
      int r = wc * PWN + n * 16 + l16;
      int h = (r >> 5) & 1;
      int g = (r & 31) | ((r >> 6) << 5);
      fb[kk][j] = *(const bf16x8*)(Bbuf + p * (BN * 128) + h * (HB * 128) +
                                   g * 128 + (((kk * 4 + ln4) ^ (g & 7)) << 4));
    }
  };
  auto MM = [&](int n0, int n1) {
    __builtin_amdgcn_s_setprio(1);
#pragma unroll
    for (int kk = 0; kk < 2; ++kk)
#pragma unroll
      for (int m = 0; m < MA; ++m) {
        acc[m][n0] = MFMA16(fa[kk][m], fb[kk][0], acc[m][n0]);
        acc[m][n1] = MFMA16(fa[kk][m], fb[kk][1], acc[m][n1]);
      }
    __builtin_amdgcn_s_setprio(0);
  };

#pragma unroll
  for (int u = 0; u < AU; ++u) stA(0, u, 0);
  stB(0, 0, 0);
  stB(0, 1, 0);

#pragma unroll 1
  for (int t = 0; t < nkt; ++t) {
    int p = t & 1, q = p ^ 1;
    bool nl = (t + 1 < nkt);
    stA(t + 1, 0, q);
    stB(t + 1, 0, q);
    if (nl) waitv<6>(); else waitv<0>();
    BAR;
    LDA(p); LDB1(p, 0, 0); LDB1(p, 1, 1);
    LGKM0; MM(0, 1);
    BAR;
    stB(t + 1, 1, q);
    if (nl) waitv<6>(); else waitv<0>();
    BAR;
    LDB1(p, 0, 2); LDB1(p, 1, 3);
    LGKM0; MM(2, 3);
    BAR;
  }
}

// -------- balanced-phase QKV GEMM core (512 thr, 8 waves, 256x256) --------
// Waves 4(M) x 2(N): per-wave 64 rows x 128 cols, frags 4m x 8n.
// Per K-tile: 4 phases, EACH exactly {<=8 ds_read_b128, 16 MFMA, 2 barriers}
// (fix for R6-R9's ~25% MfmaUtil: no phase has a 12-read serial burst).
// A-frags are register-persistent, double-set (afA/afB): tile t+1's A loaded
// from LDS during tile t's ph2/ph3 (4 reads each). B read fresh per phase
// (4 reads). Halves are bit-aligned so every wave's phase needs live in the
// same half: A-halves by row-bit5 (all waves' m0,m1 in h0), B-halves by
// row-bit6 (all waves' n0..3 in h0).
// Per-tile stage stream (into buf q=p^1): ph0: A-h0(t+1)  ph1: A-h1(t+1)
// ph2: B-h0(t+1)  ph3: B-h1(t+1)   (each = 2 GLDS/thread)
// vmcnt(4) at ph0/ph2/ph3 (oldest-first): ph0 drains B-h0(t) [needs n0..3];
// ph2 drains B-h1(t) + A-h0(t+1) [needs n4,n5 + next m0,m1]; ph3 drains
// A-h1(t+1) [next m2,m3]. Steady-state fixed point: 4 outstanding entering
// ph0. Last tile: ph0 vmcnt(2), ph2 vmcnt(0), skip stages/A'-reads.
// Stage targets' last readers are >=3 barriers earlier (race-free).
static __device__ __forceinline__ void qkv_core(
    const u16* __restrict__ A, const u16* __restrict__ Bt, int bm, int bn,
    char* __restrict__ Abuf, char* __restrict__ Bbuf, f32x4 (&acc)[4][8]) {
  constexpr int K = 2048, nkt = 32;
  int tid = threadIdx.x, lane = tid & 63, wid = tid >> 6;
  int l16 = lane & 15, ln4 = lane >> 4;
  int wr = wid >> 1, wc = wid & 1;
  const char* ga = (const char*)(A + (size_t)bm * 256 * K);
  const char* gb = (const char*)(Bt + (size_t)bn * 256 * K);
  long gs = (long)K * 2;

  auto stA = [&](int t, int h, int p) {  // rows with bit5 == h
#pragma unroll
    for (int it = 0; it < 2; ++it) {
      int c = it * 512 + tid;  // 0..1023 (128 rows x 8 chunks)
      int g = c >> 3, j = c & 7;
      int R = (g & 31) | (h << 5) | ((g >> 5) << 6);
      GLDS(ga + (long)R * gs + t * 128 + ((j ^ (g & 7)) << 4),
           Abuf + p * 32768 + h * 16384 + c * 16);
    }
  };
  auto stB = [&](int t, int h, int p) {  // rows with bit6 == h
#pragma unroll
    for (int it = 0; it < 2; ++it) {
      int c = it * 512 + tid;
      int g = c >> 3, j = c & 7;
      int R = (g & 63) | (h << 6) | ((g >> 6) << 7);
      GLDS(gb + (long)R * gs + t * 128 + ((j ^ (g & 7)) << 4),
           Bbuf + p * 32768 + h * 16384 + c * 16);
    }
  };
  auto ldA = [&](int p, int m, int kk) -> bf16x8 {
    int r = wr * 64 + m * 16 + l16;
    int h = (r >> 5) & 1, g = (r & 31) | ((r >> 6) << 5);
    return *(const bf16x8*)(Abuf + p * 32768 + h * 16384 + g * 128 +
                            (((kk * 4 + ln4) ^ (g & 7)) << 4));
  };
  auto ldB = [&](int p, int n, int kk) -> bf16x8 {
    int r = wc * 128 + n * 16 + l16;
    int h = (r >> 6) & 1, g = (r & 63) | ((r >> 7) << 6);
    return *(const bf16x8*)(Bbuf + p * 32768 + h * 16384 + g * 128 +
                            (((kk * 4 + ln4) ^ (g & 7)) << 4));
  };
  bf16x8 afA[2][4], afB[2][4];
  auto MM2 = [&](bf16x8 (&AF)[2][4], bf16x8 (&bfv)[2][2], int n0) {
    __builtin_amdgcn_s_setprio(1);
#pragma unroll
    for (int kk = 0; kk < 2; ++kk)
#pragma unroll
      for (int m = 0; m < 4; ++m) {
        acc[m][n0] = MFMA16(AF[kk][m], bfv[kk][0], acc[m][n0]);
        acc[m][n0 + 1] = MFMA16(AF[kk][m], bfv[kk][1], acc[m][n0 + 1]);
      }
    __builtin_amdgcn_s_setprio(0);
  };

#define QKV_TILE(TCUR, P, AF, AN, LAST)                                       \
  {                                                                           \
    bf16x8 bfv[2][2];                                                         \
    /* ph0: needs B-h0(t); MM n0,n1 */                                        \
    if (!(LAST)) stA((TCUR) + 1, 0, (P) ^ 1);                                 \
    if (!(LAST)) waitv<4>(); else waitv<2>();                                 \
    BAR;                                                                      \
    bfv[0][0] = ldB(P, 0, 0); bfv[0][1] = ldB(P, 1, 0);                       \
    bfv[1][0] = ldB(P, 0, 1); bfv[1][1] = ldB(P, 1, 1);                       \
    LGKM0; MM2(AF, bfv, 0); BAR;                                              \
    /* ph1: n2,n3 (B-h0, drained) */                                          \
    if (!(LAST)) stA((TCUR) + 1, 1, (P) ^ 1);                                 \
    BAR;                                                                      \
    bfv[0][0] = ldB(P, 2, 0); bfv[0][1] = ldB(P, 3, 0);                       \
    bfv[1][0] = ldB(P, 2, 1); bfv[1][1] = ldB(P, 3, 1);                       \
    LGKM0; MM2(AF, bfv, 2); BAR;                                              \
    /* ph2: needs B-h1(t) + A-h0(t+1); MM n4,n5 */                            \
    if (!(LAST)) stB((TCUR) + 1, 0, (P) ^ 1);                                 \
    if (!(LAST)) waitv<4>(); else waitv<0>();                                 \
    BAR;                                                                      \
    bfv[0][0] = ldB(P, 4, 0); bfv[0][1] = ldB(P, 5, 0);                       \
    bfv[1][0] = ldB(P, 4, 1); bfv[1][1] = ldB(P, 5, 1);                       \
    if (!(LAST)) {                                                            \
      AN[0][0] = ldA((P) ^ 1, 0, 0); AN[1][0] = ldA((P) ^ 1, 0, 1);           \
      AN[0][1] = ldA((P) ^ 1, 1, 0); AN[1][1] = ldA((P) ^ 1, 1, 1);           \
    }                                                                         \
    LGKM0; MM2(AF, bfv, 4); BAR;                                              \
    /* ph3: needs A-h1(t+1); MM n6,n7 */                                      \
    if (!(LAST)) stB((TCUR) + 1, 1, (P) ^ 1);                                 \
    if (!(LAST)) waitv<4>();                                                  \
    BAR;                                                                      \
    bfv[0][0] = ldB(P, 6, 0); bfv[0][1] = ldB(P, 7, 0);                       \
    bfv[1][0] = ldB(P, 6, 1); bfv[1][1] = ldB(P, 7, 1);                       \
    if (!(LAST)) {                                                            \
      AN[0][2] = ldA((P) ^ 1, 2, 0); AN[1][2] = ldA((P) ^ 1, 2, 1);           \
      AN[0][3] = ldA((P) ^ 1, 3, 0); AN[1][3] = ldA((P) ^ 1, 3, 1);           \
    }                                                                         \
    LGKM0; MM2(AF, bfv, 6); BAR;                                              \
  }

  // prologue: tile 0 fully into buf 0; preload afA
  stA(0, 0, 0); stA(0, 1, 0); stB(0, 0, 0); stB(0, 1, 0);
  waitv<0>();
  __syncthreads();
#pragma unroll
  for (int kk = 0; kk < 2; ++kk)
#pragma unroll
    for (int m = 0; m < 4; ++m) afA[kk][m] = ldA(0, m, kk);

#pragma unroll 1
  for (int i = 0; i < nkt / 2; ++i) {
    int ta = 2 * i;
    QKV_TILE(ta, 0, afA, afB, false);
    QKV_TILE(ta + 1, 1, afB, afA, (i == nkt / 2 - 1));
  }
#undef QKV_TILE
}

// ---------------- GEMM1: QKV projection + bias + RoPE ----------------
// C[4096,3072] = Xb @ Wqkv_t^T. BM=BN=256, waves 4(M)x2(N): per-wave 64 rows
// x 128 cols (one head-block) -> RoPE pairs (d,d+64) = acc frags (bi,bi+4)
// lane-local. Q pre-scaled by SCALE_.
__global__ __launch_bounds__(512, 2) void gemm_qkv(
    const u16* __restrict__ Xb, const u16* __restrict__ Wt,
    const float* __restrict__ bq, const float* __restrict__ bk,
    const float* __restrict__ bv, const float2* __restrict__ cstab,
    u16* __restrict__ Qh, u16* __restrict__ Kh, u16* __restrict__ Vt) {
  __shared__ __align__(16) char Abuf[2 * 256 * 128];  // 64 KB
  __shared__ __align__(16) char Bbuf[2 * 256 * 128];  // 64 KB
  int bid = blockIdx.x;
  int swz = (bid & 7) * 24 + (bid >> 3);  // XCD-contiguous chunks (192=8*24)
  int bm = swz / 12, bn = swz % 12;

  f32x4 acc[4][8] = {};
  qkv_core(Xb, Wt, bm, bn, Abuf, Bbuf, acc);

  int tid = threadIdx.x, lane = tid & 63, wid = tid >> 6;
  int l16 = lane & 15, ln4 = lane >> 4;
  int wr = wid >> 1, wc = wid & 1;

  int cb = bn * 2 + wc;  // global 128-col head-block
  int region, hh;
  const float* bias;
  if (cb < 16) {
    region = 0; hh = cb; bias = bq;
  } else if (cb < 20) {
    region = 1; hh = cb - 16; bias = bk;
  } else {
    region = 2; hh = cb - 20; bias = bv;
  }
  float postscale = (region == 0) ? SCALE_ : 1.0f;

#pragma unroll
  for (int bi = 0; bi < 4; ++bi) {
    int dlo = bi * 16 + l16;  // 0..63
    float blo = bias[hh * 128 + dlo];
    float bhi = bias[hh * 128 + dlo + 64];
#pragma unroll
    for (int m = 0; m < 4; ++m) {
      int rbase = bm * 256 + wr * 64 + m * 16 + ln4 * 4;
      int bb = rbase >> 11;   // batch
      int s0 = rbase & 2047;  // seq
      if (region == 2) {
        // V: no rope; transposed store Vt[b][kvh][d][s], 4 consecutive s
        u16 pl[4], ph[4];
#pragma unroll
        for (int reg = 0; reg < 4; ++reg) {
          pl[reg] = f2bf(acc[m][bi][reg] + blo);
          ph[reg] = f2bf(acc[m][bi + 4][reg] + bhi);
        }
        size_t base = ((size_t)(bb * NKV_ + hh) * 128 + dlo) * 2048 + s0;
        *(ushort4*)(Vt + base) = make_ushort4(pl[0], pl[1], pl[2], pl[3]);
        *(ushort4*)(Vt + base + (size_t)64 * 2048) =
            make_ushort4(ph[0], ph[1], ph[2], ph[3]);
      } else {
#pragma unroll
        for (int reg = 0; reg < 4; ++reg) {
          int rg = rbase + reg;
          int s = rg & 2047;
          float vlo = acc[m][bi][reg] + blo;
          float vhi = acc[m][bi + 4][reg] + bhi;
          float2 cs = cstab[(size_t)rg * 64 + dlo];
          float nl = (vlo * cs.x - vhi * cs.y) * postscale;
          float nh = (vhi * cs.x + vlo * cs.y) * postscale;
          u16* dst = (region == 0)
                         ? Qh + ((size_t)(bb * NH_ + hh) * 2048 + s) * 128
                         : Kh + ((size_t)(bb * NKV_ + hh) * 2048 + s) * 128;
          dst[dlo] = f2bf(nl);
          dst[dlo + 64] = f2bf(nh);
        }
      }
    }
  }
}

// ---------------- attention: causal GQA flash ----------------
// R6 version (best measured: 78.8us). 4 waves, single-buffered 40KB LDS
// (4 blocks/CU), XCD pinning (bid&7 -> (b,kvh)), defer-max softmax.
__global__ __launch_bounds__(256) void attn(const u16* __restrict__ Qh,
                                            const u16* __restrict__ Kh,
                                            const u16* __restrict__ Vt,
                                            u16* __restrict__ ctx) {
  __shared__ __align__(16) char Ks[16384];   // [64 kv][128 d] swizzled
  __shared__ __align__(16) char Vs[16384];   // [128 d][64 kv] swizzled
  __shared__ __align__(16) char Ps[4][2048]; // per-wave [16 q][64 kv]
  int bid = blockIdx.x;
  int x = bid & 7;           // XCD group = (b, kvh)
  int b = x >> 2, kvh = x & 3;
  int i = bid >> 3;          // 0..127 within XCD group
  int hl = i & 3;            // head within kv group
  int qt = 31 - (i >> 2);    // heavy q-tiles first
  int h = kvh * 4 + hl;
  int q0 = qt * 64;
  int nt = qt + 1;

  int tid = threadIdx.x, lane = tid & 63, w = tid >> 6;
  int l16 = lane & 15, ln4 = lane >> 4;

  bf16x8 qf[4];
  const u16* qrow = Qh + ((size_t)(b * NH_ + h) * 2048 + q0 + w * 16 + l16) * 128;
#pragma unroll
  for (int kk = 0; kk < 4; ++kk)
    qf[kk] = *(const bf16x8*)(qrow + kk * 32 + ln4 * 8);

  f32x4 oacc[8] = {};
  float mrow[4], lsum[4];
#pragma unroll
  for (int r = 0; r < 4; ++r) {
    mrow[r] = -1e30f;
    lsum[r] = 0.0f;
  }

  const char* kbase = (const char*)(Kh + (size_t)(b * NKV_ + kvh) * 2048 * 128);
  const char* vbase = (const char*)(Vt + (size_t)(b * NKV_ + kvh) * 128 * 2048);

#pragma unroll 1
  for (int t = 0; t < nt; ++t) {
    __syncthreads();
    stage_tile<4>(kbase + (size_t)t * 64 * 256, 256, Ks);
    stage_tile<3>(vbase + (size_t)t * 128, 4096, Vs);
    __syncthreads();

    // S = Q K^T
    f32x4 sa[4] = {};
    __builtin_amdgcn_s_setprio(1);
#pragma unroll
    for (int kk = 0; kk < 4; ++kk) {
      bf16x8 kf[4];
#pragma unroll
      for (int n = 0; n < 4; ++n) {
        int r = n * 16 + l16;
        int off = r * 256 + ((kk * 64 + ln4 * 16) ^ ((r & 7) << 4));
        kf[n] = *(const bf16x8*)(Ks + off);
      }
#pragma unroll
      for (int n = 0; n < 4; ++n) sa[n] = MFMA16(qf[kk], kf[n], sa[n]);
    }
    __builtin_amdgcn_s_setprio(0);

    if (t == nt - 1) {
#pragma unroll
      for (int n = 0; n < 4; ++n)
#pragma unroll
        for (int reg = 0; reg < 4; ++reg)
          if (t * 64 + n * 16 + l16 > q0 + w * 16 + ln4 * 4 + reg)
            sa[n][reg] = -1e30f;
    }

    // shuffle-free defer-max test
    float tloc[4];
    int ok = 1;
#pragma unroll
    for (int reg = 0; reg < 4; ++reg) {
      tloc[reg] = fmaxf(fmaxf(sa[0][reg], sa[1][reg]),
                        fmaxf(sa[2][reg], sa[3][reg]));
      ok &= (tloc[reg] <= mrow[reg] + 8.0f);
    }
    if (!__all(ok)) {
#pragma unroll
      for (int reg = 0; reg < 4; ++reg) {
        float tm = tloc[reg];
#pragma unroll
        for (int mk = 1; mk < 16; mk <<= 1) tm = fmaxf(tm, __shfl_xor(tm, mk));
        float mnew = fmaxf(mrow[reg], tm);
        float scl = __expf(mrow[reg] - mnew);
        mrow[reg] = mnew;
        lsum[reg] *= scl;
#pragma unroll
        for (int nf = 0; nf < 8; ++nf) oacc[nf][reg] *= scl;
      }
    }

    // P = exp(S - m) -> wave-private LDS; per-lane lsum partials
#pragma unroll
    for (int reg = 0; reg < 4; ++reg) {
      int prow = ln4 * 4 + reg;
      float rs = 0.0f;
#pragma unroll
      for (int n = 0; n < 4; ++n) {
        float p = __expf(sa[n][reg] - mrow[reg]);
        rs += p;
        int off = prow * 128 + ((2 * (n * 16 + l16)) ^ ((prow & 7) << 4));
        *(u16*)(Ps[w] + off) = f2bf(p);
      }
      lsum[reg] += rs;
    }

    // O += P V
    __builtin_amdgcn_s_setprio(1);
#pragma unroll
    for (int kc = 0; kc < 2; ++kc) {
      int offa = l16 * 128 + ((kc * 64 + ln4 * 16) ^ ((l16 & 7) << 4));
      bf16x8 pa = *(const bf16x8*)(Ps[w] + offa);
#pragma unroll
      for (int nf = 0; nf < 8; ++nf) {
        int r = nf * 16 + l16;
        int off = r * 128 + ((kc * 64 + ln4 * 16) ^ ((r & 7) << 4));
        bf16x8 vf = *(const bf16x8*)(Vs + off);
        oacc[nf] = MFMA16(pa, vf, oacc[nf]);
      }
    }
    __builtin_amdgcn_s_setprio(0);
  }

  // epilogue
#pragma unroll
  for (int reg = 0; reg < 4; ++reg) {
#pragma unroll
    for (int mk = 1; mk < 16; mk <<= 1)
      lsum[reg] += __shfl_xor(lsum[reg], mk);
  }
#pragma unroll
  for (int reg = 0; reg < 4; ++reg) {
    float inv = 1.0f / lsum[reg];
    int s = q0 + w * 16 + ln4 * 4 + reg;
#pragma unroll
    for (int nf = 0; nf < 8; ++nf) {
      ctx[((size_t)(b * 2048 + s)) * 2048 + h * 128 + nf * 16 + l16] =
          f2bf(oacc[nf][reg] * inv);
    }
  }
}

// ---------------- GEMM2: out = ctx @ Wo (fp32 out) ----------------
// BM=128, BN=256, waves 2(M)x4(N): per-wave 64x64. Grid = 256 blocks.
__global__ __launch_bounds__(512, 2) void gemm_out(const u16* __restrict__ Ab,
                                                   const u16* __restrict__ Wt,
                                                   float* __restrict__ out) {
  __shared__ __align__(16) char Abuf[2 * 128 * 128];  // 32 KB
  __shared__ __align__(16) char Bbuf[2 * 256 * 128];  // 64 KB
  int bid = blockIdx.x;
  int swz = (bid & 7) * 32 + (bid >> 3);  // XCD chunks (256=8*32)
  int bm = swz >> 3, bn = swz & 7;

  f32x4 acc[4][4] = {};
  gemm_rp<128, 256, 2, 4>(Ab, Wt, 2048, bm, bn, Abuf, Bbuf, acc);

  int tid = threadIdx.x, lane = tid & 63, wid = tid >> 6;
  int l16 = lane & 15, ln4 = lane >> 4;
  int wr = wid >> 2, wc = wid & 3;

#pragma unroll
  for (int m = 0; m < 4; ++m)
#pragma unroll
    for (int n = 0; n < 4; ++n)
#pragma unroll
      for (int reg = 0; reg < 4; ++reg) {
        int row = bm * 128 + wr * 64 + m * 16 + ln4 * 4 + reg;
        int col = bn * 256 + wc * 64 + n * 16 + l16;
        out[(size_t)row * 2048 + col] = acc[m][n][reg];
      }
}

// ---------------- launch ----------------

extern "C" void kernel_launch(void* const* d_in, const int* in_sizes, int n_in,
                              void* d_out, int out_size, void* d_ws,
                              size_t ws_size, hipStream_t stream) {
  const float* hid = (const float*)d_in[0];
  const int* pos = (const int*)d_in[1];
  const float* Wq = (const float*)d_in[2];
  const float* bq = (const float*)d_in[3];
  const float* Wk = (const float*)d_in[4];
  const float* bk = (const float*)d_in[5];
  const float* Wv = (const float*)d_in[6];
  const float* bv = (const float*)d_in[7];
  const float* Wo = (const float*)d_in[8];
  float* out = (float*)d_out;

  char* ws = (char*)d_ws;
  u16* Xb = (u16*)(ws + 0);                    // 16.78 MB  [4096][2048] bf16
  u16* Wqkvt = (u16*)(ws + 16777216UL);        // 12.58 MB  [3072][2048] bf16
  u16* Wot = (u16*)(ws + 29360128UL);          //  8.39 MB  [2048][2048] bf16
  u16* Qh = (u16*)(ws + 37748736UL);           // 16.78 MB  [B][NH][S][D]
  u16* Kh = (u16*)(ws + 54525952UL);           //  4.19 MB  [B][NKV][S][D]
  u16* Vt = (u16*)(ws + 58720256UL);           //  4.19 MB  [B][NKV][D][S]
  float2* cstab = (float2*)(ws + 62914560UL);  //  2.10 MB  [B*S][64]
  u16* ctx = Xb;  // alias: Xb dead after gemm_qkv

  conv_x<<<8192, 256, 0, stream>>>(hid, Xb);
  transpose_bf16<<<dim3(64, 64), dim3(32, 8), 0, stream>>>(Wq, Wqkvt, 2048,
                                                           2048);
  transpose_bf16<<<dim3(16, 64), dim3(32, 8), 0, stream>>>(
      Wk, Wqkvt + (size_t)2048 * 2048, 2048, 512);
  transpose_bf16<<<dim3(16, 64), dim3(32, 8), 0, stream>>>(
      Wv, Wqkvt + (size_t)2560 * 2048, 2048, 512);
  transpose_bf16<<<dim3(64, 64), dim3(32, 8), 0, stream>>>(Wo, Wot, 2048, 2048);
  prep_cstab<<<1024, 256, 0, stream>>>(pos, cstab);

  gemm_qkv<<<192, 512, 0, stream>>>(Xb, Wqkvt, bq, bk, bv, cstab, Qh, Kh, Vt);
  attn<<<1024, 256, 0, stream>>>(Qh, Kh, Vt, ctx);
  gemm_out<<<256, 512, 0, stream>>>(ctx, Wot, out);
}